// Round 2
// baseline (175.832 us; speedup 1.0000x reference)
//
#include <hip/hip_runtime.h>

// Problem constants
#define NB 2
#define CC 512
#define NN 2304
#define NH 8
#define DD 16
#define TT 128          // NH*DD
#define O3 384          // 3*TT

typedef __attribute__((ext_vector_type(4))) float f32x4;
typedef __attribute__((ext_vector_type(8))) __bf16 bf16x8;
typedef __attribute__((ext_vector_type(4))) __bf16 bf16x4;

static __device__ __forceinline__ bf16x8 zero8() {
    bf16x8 z;
#pragma unroll
    for (int i = 0; i < 8; i++) z[i] = (__bf16)0.0f;
    return z;
}

// ---------------------------------------------------------------------------
// Kernel 0: convert x [b,c,n] fp32 -> xT [b,n,c] bf16 (LDS tile transpose),
//           plus straight fp32->bf16 conversion of w_qkv and w_out.
// ---------------------------------------------------------------------------
__global__ __launch_bounds__(256) void k0_convert(
    const float* __restrict__ x, const float* __restrict__ wqkv,
    const float* __restrict__ wout,
    __bf16* __restrict__ xT, __bf16* __restrict__ wqb, __bf16* __restrict__ wob)
{
    int bid = blockIdx.x;
    int t = threadIdx.x;
    if (bid < 576) {
        __shared__ float tile[64][65];
        int b = bid / 288, rem = bid % 288;
        int nt = rem / 8, cb = rem % 8;
        int n0 = nt * 64, c0 = cb * 64;
        int tc = t >> 6, tn = t & 63;
#pragma unroll
        for (int i = 0; i < 16; i++) {
            int cl = i * 4 + tc;
            tile[cl][tn] = x[(size_t)(b * CC + c0 + cl) * NN + n0 + tn];
        }
        __syncthreads();
#pragma unroll
        for (int i = 0; i < 16; i++) {
            int nl = i * 4 + tc;
            xT[(size_t)(b * NN + n0 + nl) * CC + c0 + tn] = (__bf16)tile[tn][nl];
        }
    } else {
        int wid = bid - 576;
        int base = wid * 256 + t;
#pragma unroll
        for (int i = 0; i < 16; i++) {
            int j = base + i * 16384;           // covers 262144 = 384*512 + 512*128
            if (j < O3 * CC) wqb[j] = (__bf16)wqkv[j];
            else             wob[j - O3 * CC] = (__bf16)wout[j - O3 * CC];
        }
    }
}

// ---------------------------------------------------------------------------
// Kernel 1: QKV GEMM  qkvT[n,o] = sum_c xT[n,c] * W[o,c]  (per batch),
//           fused per-head L2 norm of q,k.  Outputs:
//           Q,K: [bh][n][16] bf16 ;  VT: [bh][16][n] bf16
// ---------------------------------------------------------------------------
__global__ __launch_bounds__(256) void k1_qkv(
    const __bf16* __restrict__ xT, const __bf16* __restrict__ wqb,
    __bf16* __restrict__ Q, __bf16* __restrict__ K, __bf16* __restrict__ VT)
{
    int ob = blockIdx.x, nt = blockIdx.y, b = blockIdx.z;
    int lane = threadIdx.x & 63, wave = threadIdx.x >> 6;
    int quad = lane >> 4, col = lane & 15;
    int n0 = nt * 64 + wave * 16;
    int o0 = ob * 96;

    f32x4 acc[6];
#pragma unroll
    for (int s = 0; s < 6; s++) acc[s] = (f32x4){0.f, 0.f, 0.f, 0.f};

    const __bf16* arow = xT + (size_t)(b * NN + n0 + col) * CC + quad * 8;
#pragma unroll 4
    for (int ks = 0; ks < 16; ks++) {
        bf16x8 a = *(const bf16x8*)(arow + ks * 32);
#pragma unroll
        for (int s = 0; s < 6; s++) {
            bf16x8 bb = *(const bf16x8*)(wqb + (size_t)(o0 + s * 16 + col) * CC + ks * 32 + quad * 8);
            acc[s] = __builtin_amdgcn_mfma_f32_16x16x32_bf16(a, bb, acc[s], 0, 0, 0);
        }
    }

#pragma unroll
    for (int s = 0; s < 6; s++) {
        int oc = o0 + s * 16 + col;
        int d = oc & 15, h = (oc >> 4) & 7, kind = oc >> 7;  // 0=q 1=k 2=v
        f32x4 v = acc[s];
        if (kind < 2) {
            // row sums of squares over the 16 d-columns (16 lanes of this quad)
            float ss0 = v[0] * v[0], ss1 = v[1] * v[1], ss2 = v[2] * v[2], ss3 = v[3] * v[3];
#pragma unroll
            for (int m = 1; m < 16; m <<= 1) {
                ss0 += __shfl_xor(ss0, m);
                ss1 += __shfl_xor(ss1, m);
                ss2 += __shfl_xor(ss2, m);
                ss3 += __shfl_xor(ss3, m);
            }
            v[0] *= 1.0f / fmaxf(sqrtf(ss0), 1e-12f);
            v[1] *= 1.0f / fmaxf(sqrtf(ss1), 1e-12f);
            v[2] *= 1.0f / fmaxf(sqrtf(ss2), 1e-12f);
            v[3] *= 1.0f / fmaxf(sqrtf(ss3), 1e-12f);
            __bf16* dst = (kind == 0 ? Q : K) + (size_t)(b * NH + h) * NN * DD;
#pragma unroll
            for (int r = 0; r < 4; r++) {
                int n = n0 + quad * 4 + r;
                dst[(size_t)n * DD + d] = (__bf16)v[r];
            }
        } else {
            bf16x4 pk;
#pragma unroll
            for (int r = 0; r < 4; r++) pk[r] = (__bf16)v[r];
            int n = n0 + quad * 4;
            *(bf16x4*)(VT + (size_t)((b * NH + h) * DD + d) * NN + n) = pk;
        }
    }
}

// ---------------------------------------------------------------------------
// Kernel 2: attention (flash-lite; |logit| <= temp so no max subtraction).
// Grid: (36 q-tiles, 16 bh). Each wave owns 16 q-rows. K/V chunks (32 tokens)
// staged in LDS; P transposed C-layout -> A-layout via wave-private LDS tile.
// Output AO: [b][n][t=h*16+d] bf16
// ---------------------------------------------------------------------------
__global__ __launch_bounds__(256) void k2_attn(
    const __bf16* __restrict__ Q, const __bf16* __restrict__ K,
    const __bf16* __restrict__ VT, const float* __restrict__ temp,
    __bf16* __restrict__ AO)
{
    int qt = blockIdx.x, bh = blockIdx.y;
    int b = bh >> 3, h = bh & 7;
    int t = threadIdx.x;
    int lane = t & 63, wave = t >> 6, quad = lane >> 4, col = lane & 15;

    __shared__ __attribute__((aligned(16))) __bf16 lK[32 * 24];     // rows padded to 48B
    __shared__ __attribute__((aligned(16))) __bf16 lV[16 * 40];     // rows padded to 80B
    __shared__ __attribute__((aligned(16))) __bf16 lP[4][16 * 32];  // per-wave P tile, stride 32
    // NOTE: lP row stride MUST be >= 32 (16 rows x 32 keys). Stride 24 (round 1)
    // made row r's keys 16..31 collide with row r+1's keys 0..7 -> absmax 2.78.

    const __bf16* Qb = Q + (size_t)bh * NN * DD;
    const __bf16* Kb = K + (size_t)bh * NN * DD;
    const __bf16* Vb = VT + (size_t)bh * DD * NN;
    float tmp = temp[h];

    bf16x8 aq = zero8();
    int qrow = qt * 64 + wave * 16 + col;
    if (quad < 2) aq = *(const bf16x8*)(Qb + (size_t)qrow * DD + quad * 8);

    f32x4 o_acc = {0.f, 0.f, 0.f, 0.f};
    f32x4 l_acc = {0.f, 0.f, 0.f, 0.f};
    const f32x4 zc = {0.f, 0.f, 0.f, 0.f};

    for (int kt = 0; kt < NN / 32; kt++) {
        // ---- stage K (32x16) and V^T (16x32) chunk to LDS ----
        if (t < 128) {
            int tok = t >> 2, seg = t & 3;
            *(bf16x4*)(lK + tok * 24 + seg * 4) =
                *(const bf16x4*)(Kb + (size_t)(kt * 32 + tok) * DD + seg * 4);
        } else {
            int u = t - 128, d = u >> 3, seg = u & 7;
            *(bf16x4*)(lV + d * 40 + seg * 4) =
                *(const bf16x4*)(Vb + (size_t)d * NN + kt * 32 + seg * 4);
        }
        __syncthreads();

        // ---- S = Q K^T (d padded to 32 with zeros) ----
        bf16x8 k0 = zero8(), k1 = zero8();
        if (quad < 2) {
            k0 = *(const bf16x8*)(lK + col * 24 + quad * 8);
            k1 = *(const bf16x8*)(lK + (16 + col) * 24 + quad * 8);
        }
        f32x4 s0 = __builtin_amdgcn_mfma_f32_16x16x32_bf16(aq, k0, zc, 0, 0, 0);
        f32x4 s1 = __builtin_amdgcn_mfma_f32_16x16x32_bf16(aq, k1, zc, 0, 0, 0);

        // ---- P = exp(temp*S); accumulate row-sum of the ROUNDED P so the
        //      numerator (bf16 P times V) and denominator stay consistent ----
        __bf16* Pw = lP[wave];
#pragma unroll
        for (int r = 0; r < 4; r++) {
            __bf16 p0 = (__bf16)__expf(tmp * s0[r]);
            __bf16 p1 = (__bf16)__expf(tmp * s1[r]);
            l_acc[r] += (float)p0 + (float)p1;
            Pw[(quad * 4 + r) * 32 + col] = p0;
            Pw[(quad * 4 + r) * 32 + 16 + col] = p1;
        }
        asm volatile("s_waitcnt lgkmcnt(0)" ::: "memory");

        // ---- O += P V ----
        bf16x8 pa = *(const bf16x8*)(Pw + col * 32 + quad * 8);
        bf16x8 vf = *(const bf16x8*)(lV + col * 40 + quad * 8);
        o_acc = __builtin_amdgcn_mfma_f32_16x16x32_bf16(pa, vf, o_acc, 0, 0, 0);
        __syncthreads();
    }

    // final denominator: reduce across the 16 cols (lanes of this quad)
    f32x4 ls = l_acc;
#pragma unroll
    for (int m = 1; m < 16; m <<= 1) {
        ls[0] += __shfl_xor(ls[0], m);
        ls[1] += __shfl_xor(ls[1], m);
        ls[2] += __shfl_xor(ls[2], m);
        ls[3] += __shfl_xor(ls[3], m);
    }
    __bf16* aob = AO + (size_t)b * NN * TT + h * DD;
#pragma unroll
    for (int r = 0; r < 4; r++) {
        int n = qt * 64 + wave * 16 + quad * 4 + r;
        aob[(size_t)n * TT + col] = (__bf16)(o_acc[r] / ls[r]);
    }
}

// ---------------------------------------------------------------------------
// Kernel 3: projection  out[b,c,n] = sum_t w_out[c,t] * AO[b,n,t]  (pre-BN fp32
// written straight into d_out; C-layout regs -> contiguous-n float4 stores)
// ---------------------------------------------------------------------------
__global__ __launch_bounds__(256) void k3_proj(
    const __bf16* __restrict__ AO, const __bf16* __restrict__ wob,
    float* __restrict__ out)
{
    int cb = blockIdx.x, nt = blockIdx.y, b = blockIdx.z;
    int lane = threadIdx.x & 63, wave = threadIdx.x >> 6;
    int quad = lane >> 4, col = lane & 15;
    int n0 = nt * 64 + wave * 16, c0 = cb * 64;

    f32x4 acc[4];
#pragma unroll
    for (int s = 0; s < 4; s++) acc[s] = (f32x4){0.f, 0.f, 0.f, 0.f};

    const __bf16* ab = AO + (size_t)(b * NN + n0 + col) * TT + quad * 8;
#pragma unroll
    for (int ks = 0; ks < 4; ks++) {
        bf16x8 a = *(const bf16x8*)(ab + ks * 32);
#pragma unroll
        for (int s = 0; s < 4; s++) {
            bf16x8 bb = *(const bf16x8*)(wob + (size_t)(c0 + s * 16 + col) * TT + ks * 32 + quad * 8);
            acc[s] = __builtin_amdgcn_mfma_f32_16x16x32_bf16(a, bb, acc[s], 0, 0, 0);
        }
    }
#pragma unroll
    for (int s = 0; s < 4; s++) {
        int c = c0 + s * 16 + col;
        float* dst = out + (size_t)(b * CC + c) * NN + n0 + quad * 4;
        *(f32x4*)dst = acc[s];
    }
}

// ---------------------------------------------------------------------------
// Kernel 4: training-mode BatchNorm, in place on d_out. One block per channel;
// 4608 values live in registers across the stats reduction.
// ---------------------------------------------------------------------------
__global__ __launch_bounds__(256) void k4_bn(
    float* __restrict__ out, const float* __restrict__ gamma,
    const float* __restrict__ beta)
{
    int c = blockIdx.x;
    int t = threadIdx.x;
    float vals[18];
    float s = 0.f, q = 0.f;
#pragma unroll
    for (int i = 0; i < 18; i++) {
        int j = i * 256 + t;          // 0..4607 over (b,n)
        int b = j / NN, n = j % NN;
        float v = out[(size_t)(b * CC + c) * NN + n];
        vals[i] = v; s += v; q += v * v;
    }
#pragma unroll
    for (int m = 1; m < 64; m <<= 1) { s += __shfl_xor(s, m); q += __shfl_xor(q, m); }
    __shared__ float rs[4], rq[4];
    int lane = t & 63, wave = t >> 6;
    if (lane == 0) { rs[wave] = s; rq[wave] = q; }
    __syncthreads();
    s = rs[0] + rs[1] + rs[2] + rs[3];
    q = rq[0] + rq[1] + rq[2] + rq[3];
    float mean = s * (1.0f / 4608.0f);
    float var = q * (1.0f / 4608.0f) - mean * mean;
    float sc = rsqrtf(var + 1e-5f) * gamma[c];
    float sh = beta[c] - mean * sc;
#pragma unroll
    for (int i = 0; i < 18; i++) {
        int j = i * 256 + t;
        int b = j / NN, n = j % NN;
        out[(size_t)(b * CC + c) * NN + n] = vals[i] * sc + sh;
    }
}

// ---------------------------------------------------------------------------
extern "C" void kernel_launch(void* const* d_in, const int* in_sizes, int n_in,
                              void* d_out, int out_size, void* d_ws, size_t ws_size,
                              hipStream_t stream) {
    const float* x     = (const float*)d_in[0];
    const float* wqkv  = (const float*)d_in[1];
    const float* temp  = (const float*)d_in[2];
    const float* wout  = (const float*)d_in[3];
    const float* gamma = (const float*)d_in[4];
    const float* beta  = (const float*)d_in[5];
    float* out = (float*)d_out;

    char* ws = (char*)d_ws;
    // workspace layout (bytes)
    const size_t OFF_XT = 0;                 // 2*2304*512*2   = 4,718,592
    const size_t OFF_WQ = 4718592;           // 384*512*2      =   393,216
    const size_t OFF_WO = 5111808;           // 512*128*2      =   131,072
    const size_t OFF_Q  = 5242880;           // 2*8*2304*16*2  = 1,179,648
    const size_t OFF_K  = 6422528;
    const size_t OFF_VT = 7602176;
    const size_t OFF_AO = 8781824;           // 2*2304*128*2   = 1,179,648 -> end 9,961,472

    __bf16* xT  = (__bf16*)(ws + OFF_XT);
    __bf16* wqb = (__bf16*)(ws + OFF_WQ);
    __bf16* wob = (__bf16*)(ws + OFF_WO);
    __bf16* Q   = (__bf16*)(ws + OFF_Q);
    __bf16* K   = (__bf16*)(ws + OFF_K);
    __bf16* VT  = (__bf16*)(ws + OFF_VT);
    __bf16* AO  = (__bf16*)(ws + OFF_AO);

    k0_convert<<<640, 256, 0, stream>>>(x, wqkv, wout, xT, wqb, wob);
    k1_qkv<<<dim3(4, 36, 2), 256, 0, stream>>>(xT, wqb, Q, K, VT);
    k2_attn<<<dim3(36, 16), 256, 0, stream>>>(Q, K, VT, temp, AO);
    k3_proj<<<dim3(8, 36, 2), 256, 0, stream>>>(AO, wob, out);
    k4_bn<<<512, 256, 0, stream>>>(out, gamma, beta);
}